// Round 10
// baseline (112.431 us; speedup 1.0000x reference)
//
#include <hip/hip_runtime.h>
#include <hip/hip_fp16.h>

// Bicubic (Catmull-Rom) warp, faithful to the reference's tile/reshape quirk:
// output plane k uses IMAGE plane k warped with DELTA plane (k % B).
//
// Round-10: software-pipelined tile strip (T14 async-STAGE split).
// Each 1024-thread block owns a 64-wide x 128-tall strip = 8 tiles of 64x16.
// Double-buffered fp16 channel-packed halo (2 x 30x82 cells = 39.4 KB).
// Per iteration: issue NEXT tile's staging global loads + delta loads into
// REGISTERS (no barrier between issue and use -> they stay in flight),
// compute CURRENT tile from LDS (taps: one ds_read_b64 per cell, ~500 cyc),
// then vmcnt-wait + convert + ds_write the next buffer, barrier, repeat.
// This removes the round-9 convoy: stage (VMEM latency) -> barrier ->
// compute (LDS+VALU) serialization that left every pipe <65% busy.
// Bonus: consecutive tiles in a strip share 14 halo rows -> L1/L2 reuse.
//
// LDS conflicts (~1.38e7 cyc/dispatch) are the irreducible balls-in-bins
// imbalance of per-lane jittered tap addresses (rounds 5-9: layout no-ops).
//
// Coordinates: xm = x + dx directly (the reference's normalize->unnormalize
// roundtrip is an algebraic identity; fp deviation ~1e-4 px vs 0.1 abs
// threshold). Halo covers |delta| < ~6 (P ~ 2e-9/px); per-lane clamped f32
// global fallback otherwise.

#define TLH 16     // tile height
#define TPB 8      // tiles per block (strip height 128)
#define RTY 7      // top margin (rows above tile top)
#define RWS 30     // halo rows
#define RTX 8      // left margin
#define CLS 80     // halo cols (20 quads)
#define STR 82     // LDS row stride in cells (656 B, 16B-multiple)
#define NQ  (RWS * (CLS / 4))   // 600 staging quads

struct alignas(8) Cell {
    __half2 a;   // (ch0, ch1)
    __half2 b;   // (ch2, 0)
};
struct alignas(16) Cell2 { Cell c0, c1; };

__device__ __forceinline__ void cubic_coeffs(float t, float c[4]) {
    float t2 = t * t;
    float t3 = t2 * t;
    c[0] = (-t3 + 2.0f * t2 - t) * 0.5f;
    c[1] = (3.0f * t3 - 5.0f * t2 + 2.0f) * 0.5f;
    c[2] = (-3.0f * t3 + 4.0f * t2 + t) * 0.5f;
    c[3] = 1.0f - (c[0] + c[1] + c[2]);
}

__global__ __launch_bounds__(1024, 8) void warp_bicubic_kernel(
    const float* __restrict__ img,
    const float* __restrict__ dx,
    const float* __restrict__ dy,
    float* __restrict__ out,
    int B, int C, int H, int W)
{
    __shared__ Cell lds[2][RWS * STR];   // 39360 B -> 2 blocks/CU

    const int tx = threadIdx.x;              // 0..63
    const int ty = threadIdx.y;              // 0..15
    const int tid = ty * 64 + tx;
    const int X  = blockIdx.x * 64;
    const int Y0 = blockIdx.y * (TLH * TPB);
    const int db = blockIdx.z;
    const int hw = H * W;

    const float* __restrict__ ch0 = img + (size_t)db * hw;
    const float* __restrict__ ch1 = img + (size_t)(db + B) * hw;
    const float* __restrict__ ch2 = img + (size_t)(db + 2 * B) * hw;

    const int x = X + tx;

    // staging geometry (fixed per thread)
    const bool sact = tid < NQ;
    const int sr   = tid / 20;               // halo row
    const int sqc  = tid - sr * 20;          // quad col
    const int sgx0 = X - RTX + 4 * sqc;      // 16B-aligned when in-bounds

    float4 v0, v1, v2;                       // staging registers (in flight)
    float fdx_n, fdy_n;                      // next tile's delta

    auto issue_delta = [&](int t) {
        int y = Y0 + t * TLH + ty;
        int dofs = db * hw + y * W + x;
        fdx_n = dx[dofs];
        fdy_n = dy[dofs];
    };

    auto issue_stage = [&](int t) {
        if (!sact) return;
        int gy = Y0 + t * TLH - RTY + sr;
        if (gy >= 0 && gy < H && sgx0 >= 0 && sgx0 <= W - 4) {
            size_t off = (size_t)gy * W + sgx0;
            v0 = *(const float4*)(ch0 + off);
            v1 = *(const float4*)(ch1 + off);
            v2 = *(const float4*)(ch2 + off);
        } else {
            int gyc = min(max(gy, 0), H - 1);
            float e0[4], e1[4], e2[4];
#pragma unroll
            for (int e = 0; e < 4; ++e) {
                int gxc = min(max(sgx0 + e, 0), W - 1);
                size_t off = (size_t)gyc * W + gxc;
                e0[e] = ch0[off]; e1[e] = ch1[off]; e2[e] = ch2[off];
            }
            v0 = make_float4(e0[0], e0[1], e0[2], e0[3]);
            v1 = make_float4(e1[0], e1[1], e1[2], e1[3]);
            v2 = make_float4(e2[0], e2[1], e2[2], e2[3]);
        }
    };

    auto write_stage = [&](int buf) {
        if (!sact) return;
        Cell cells[4];
        cells[0].a = __floats2half2_rn(v0.x, v1.x);
        cells[0].b = __floats2half2_rn(v2.x, 0.0f);
        cells[1].a = __floats2half2_rn(v0.y, v1.y);
        cells[1].b = __floats2half2_rn(v2.y, 0.0f);
        cells[2].a = __floats2half2_rn(v0.z, v1.z);
        cells[2].b = __floats2half2_rn(v2.z, 0.0f);
        cells[3].a = __floats2half2_rn(v0.w, v1.w);
        cells[3].b = __floats2half2_rn(v2.w, 0.0f);
        Cell2* dst = (Cell2*)&lds[buf][sr * STR + 4 * sqc];   // 16B-aligned
        dst[0] = *(const Cell2*)&cells[0];
        dst[1] = *(const Cell2*)&cells[2];
    };

    auto compute_tile = [&](int t, int buf, float fdx, float fdy) {
        const int Yt = Y0 + t * TLH;
        const int y = Yt + ty;
        const int pos = y * W + x;

        const float xm = (float)x + fdx;
        const float ym = (float)y + fdy;
        const float x0f = floorf(xm);
        const float y0f = floorf(ym);
        const float tfx = xm - x0f;
        const float tfy = ym - y0f;

        float cx[4], cy[4];
        cubic_coeffs(tfx, cx);
        cubic_coeffs(tfy, cy);

        const int x0 = (int)x0f;
        const int y0 = (int)y0f;

        float a0, a1, a2;

        const unsigned ulx = (unsigned)(x0 - X + (RTX - 1));
        const unsigned uly = (unsigned)(y0 - Yt + (RTY - 1));

        if (ulx <= (unsigned)(CLS - 4) && uly <= (unsigned)(RWS - 4)) {
            const Cell* __restrict__ base = &lds[buf][uly * STR + ulx];
            __half2 cxh[4], cyh[4];
#pragma unroll
            for (int j = 0; j < 4; ++j) {
                cxh[j] = __float2half2_rn(cx[j]);
                cyh[j] = __float2half2_rn(cy[j]);
            }
            __half2 acc01 = __float2half2_rn(0.0f);
            __half2 acc2  = __float2half2_rn(0.0f);
#pragma unroll
            for (int i = 0; i < 4; ++i) {
                const Cell* __restrict__ row = base + i * STR;
                Cell t0 = row[0];
                Cell t1 = row[1];
                Cell t2 = row[2];
                Cell t3 = row[3];
                __half2 r01 = __hmul2(cxh[0], t0.a);
                r01 = __hfma2(cxh[1], t1.a, r01);
                r01 = __hfma2(cxh[2], t2.a, r01);
                r01 = __hfma2(cxh[3], t3.a, r01);
                __half2 r2 = __hmul2(cxh[0], t0.b);
                r2 = __hfma2(cxh[1], t1.b, r2);
                r2 = __hfma2(cxh[2], t2.b, r2);
                r2 = __hfma2(cxh[3], t3.b, r2);
                acc01 = __hfma2(cyh[i], r01, acc01);
                acc2  = __hfma2(cyh[i], r2, acc2);
            }
            a0 = __low2float(acc01);
            a1 = __high2float(acc01);
            a2 = __low2float(acc2);
        } else {
            // rare tail (|delta| >= ~6): direct clamped f32 global gathers
            a0 = a1 = a2 = 0.0f;
            int xs[4], rowoff[4];
#pragma unroll
            for (int o = 0; o < 4; ++o) {
                xs[o] = min(max(x0 - 1 + o, 0), W - 1);
                rowoff[o] = min(max(y0 - 1 + o, 0), H - 1) * W;
            }
#pragma unroll
            for (int i = 0; i < 4; ++i) {
                float w0 = cy[i] * cx[0], w1 = cy[i] * cx[1];
                float w2 = cy[i] * cx[2], w3 = cy[i] * cx[3];
                const float* r0 = ch0 + rowoff[i];
                const float* r1 = ch1 + rowoff[i];
                const float* r2 = ch2 + rowoff[i];
                a0 = fmaf(w0, r0[xs[0]], a0); a0 = fmaf(w1, r0[xs[1]], a0);
                a0 = fmaf(w2, r0[xs[2]], a0); a0 = fmaf(w3, r0[xs[3]], a0);
                a1 = fmaf(w0, r1[xs[0]], a1); a1 = fmaf(w1, r1[xs[1]], a1);
                a1 = fmaf(w2, r1[xs[2]], a1); a1 = fmaf(w3, r1[xs[3]], a1);
                a2 = fmaf(w0, r2[xs[0]], a2); a2 = fmaf(w1, r2[xs[1]], a2);
                a2 = fmaf(w2, r2[xs[2]], a2); a2 = fmaf(w3, r2[xs[3]], a2);
            }
        }

        out[(size_t)db * hw + pos] = a0;
        out[(size_t)(db + B) * hw + pos] = a1;
        out[(size_t)(db + 2 * B) * hw + pos] = a2;
    };

    // ---- prologue: stage tile 0 ----
    issue_delta(0);
    issue_stage(0);
    write_stage(0);
    __syncthreads();

    // ---- pipelined main loop ----
    for (int t = 0; t < TPB; ++t) {
        const float fdx = fdx_n;
        const float fdy = fdy_n;
        if (t + 1 < TPB) {
            issue_delta(t + 1);      // loads stay in flight during compute
            issue_stage(t + 1);
        }
        compute_tile(t, t & 1, fdx, fdy);
        if (t + 1 < TPB) {
            write_stage((t + 1) & 1);   // vmcnt wait happens here, post-compute
        }
        __syncthreads();
    }
}

extern "C" void kernel_launch(void* const* d_in, const int* in_sizes, int n_in,
                              void* d_out, int out_size, void* d_ws, size_t ws_size,
                              hipStream_t stream) {
    const float* img = (const float*)d_in[0];
    const float* dx  = (const float*)d_in[1];
    const float* dy  = (const float*)d_in[2];
    float* out = (float*)d_out;

    const int B = 8, C = 3, H = 1024, W = 1024;
    dim3 block(64, 16, 1);
    dim3 grid(W / 64, H / (TLH * TPB), B);
    warp_bicubic_kernel<<<grid, block, 0, stream>>>(img, dx, dy, out, B, C, H, W);
}

// Round 11
// 102.949 us; speedup vs baseline: 1.0921x; 1.0921x over previous
//
#include <hip/hip_runtime.h>
#include <hip/hip_fp16.h>

// Bicubic (Catmull-Rom) warp, faithful to the reference's tile/reshape quirk:
// output plane k uses IMAGE plane k warped with DELTA plane (k % B).
//
// Round-11: round-10's software-pipelined tile strip (T14 async-STAGE split)
// with the SPILL FIXED. Round-10 postmortem: __launch_bounds__(1024,8)
// forced a 32-VGPR allocation target; the 12 in-flight staging VGPRs spilled
// to scratch (+64 MB HBM writes, +72 MB fetch) and the round-trip erased the
// pipeline win. Fix: __launch_bounds__(1024, 6) caps the allocator at ~85
// VGPRs so the needed ~48 allocate cleanly; achieved occupancy is still
// 2 blocks/CU (32 waves) since actual VGPR use stays <= 64 and LDS is
// 39.4 KB/block.
//
// Structure: each 1024-thread block owns a 64-wide x 128-tall strip =
// 8 tiles of 64x16. Double-buffered fp16 channel-packed halo (2 x 30x82
// cells). Per iteration: issue NEXT tile's staging global loads + delta
// loads into REGISTERS (stay in flight through compute), compute CURRENT
// tile from LDS (one ds_read_b64 per tap), then convert + ds_write the next
// buffer (vmcnt wait lands here, post-compute), barrier, repeat.
//
// LDS conflicts (~1.38e7 cyc/dispatch) are the irreducible balls-in-bins
// imbalance of per-lane jittered tap addresses (rounds 5-10: layout no-ops).
//
// Coordinates: xm = x + dx directly (the reference's normalize->unnormalize
// roundtrip is an algebraic identity; fp deviation ~1e-4 px vs 0.1 abs
// threshold). Halo covers |delta| < ~6 (P ~ 2e-9/px); per-lane clamped f32
// global fallback otherwise.

#define TLH 16     // tile height
#define TPB 8      // tiles per block (strip height 128)
#define RTY 7      // top margin (rows above tile top)
#define RWS 30     // halo rows
#define RTX 8      // left margin
#define CLS 80     // halo cols (20 quads)
#define STR 82     // LDS row stride in cells (656 B, 16B-multiple)
#define NQ  (RWS * (CLS / 4))   // 600 staging quads

struct alignas(8) Cell {
    __half2 a;   // (ch0, ch1)
    __half2 b;   // (ch2, 0)
};
struct alignas(16) Cell2 { Cell c0, c1; };

__device__ __forceinline__ void cubic_coeffs(float t, float c[4]) {
    float t2 = t * t;
    float t3 = t2 * t;
    c[0] = (-t3 + 2.0f * t2 - t) * 0.5f;
    c[1] = (3.0f * t3 - 5.0f * t2 + 2.0f) * 0.5f;
    c[2] = (-3.0f * t3 + 4.0f * t2 + t) * 0.5f;
    c[3] = 1.0f - (c[0] + c[1] + c[2]);
}

__global__ __launch_bounds__(1024, 6) void warp_bicubic_kernel(
    const float* __restrict__ img,
    const float* __restrict__ dx,
    const float* __restrict__ dy,
    float* __restrict__ out,
    int B, int C, int H, int W)
{
    __shared__ Cell lds[2][RWS * STR];   // 39360 B -> 2 blocks/CU

    const int tx = threadIdx.x;              // 0..63
    const int ty = threadIdx.y;              // 0..15
    const int tid = ty * 64 + tx;
    const int X  = blockIdx.x * 64;
    const int Y0 = blockIdx.y * (TLH * TPB);
    const int db = blockIdx.z;
    const int hw = H * W;

    const float* __restrict__ ch0 = img + (size_t)db * hw;
    const float* __restrict__ ch1 = img + (size_t)(db + B) * hw;
    const float* __restrict__ ch2 = img + (size_t)(db + 2 * B) * hw;

    const int x = X + tx;

    // staging geometry (fixed per thread)
    const bool sact = tid < NQ;
    const int sr   = tid / 20;               // halo row
    const int sqc  = tid - sr * 20;          // quad col
    const int sgx0 = X - RTX + 4 * sqc;      // 16B-aligned when in-bounds

    float4 v0, v1, v2;                       // staging registers (in flight)
    float fdx_n, fdy_n;                      // next tile's delta

    auto issue_delta = [&](int t) {
        int y = Y0 + t * TLH + ty;
        int dofs = db * hw + y * W + x;
        fdx_n = dx[dofs];
        fdy_n = dy[dofs];
    };

    auto issue_stage = [&](int t) {
        if (!sact) return;
        int gy = Y0 + t * TLH - RTY + sr;
        if (gy >= 0 && gy < H && sgx0 >= 0 && sgx0 <= W - 4) {
            size_t off = (size_t)gy * W + sgx0;
            v0 = *(const float4*)(ch0 + off);
            v1 = *(const float4*)(ch1 + off);
            v2 = *(const float4*)(ch2 + off);
        } else {
            int gyc = min(max(gy, 0), H - 1);
            float e0[4], e1[4], e2[4];
#pragma unroll
            for (int e = 0; e < 4; ++e) {
                int gxc = min(max(sgx0 + e, 0), W - 1);
                size_t off = (size_t)gyc * W + gxc;
                e0[e] = ch0[off]; e1[e] = ch1[off]; e2[e] = ch2[off];
            }
            v0 = make_float4(e0[0], e0[1], e0[2], e0[3]);
            v1 = make_float4(e1[0], e1[1], e1[2], e1[3]);
            v2 = make_float4(e2[0], e2[1], e2[2], e2[3]);
        }
    };

    auto write_stage = [&](int buf) {
        if (!sact) return;
        Cell cells[4];
        cells[0].a = __floats2half2_rn(v0.x, v1.x);
        cells[0].b = __floats2half2_rn(v2.x, 0.0f);
        cells[1].a = __floats2half2_rn(v0.y, v1.y);
        cells[1].b = __floats2half2_rn(v2.y, 0.0f);
        cells[2].a = __floats2half2_rn(v0.z, v1.z);
        cells[2].b = __floats2half2_rn(v2.z, 0.0f);
        cells[3].a = __floats2half2_rn(v0.w, v1.w);
        cells[3].b = __floats2half2_rn(v2.w, 0.0f);
        Cell2* dst = (Cell2*)&lds[buf][sr * STR + 4 * sqc];   // 16B-aligned
        dst[0] = *(const Cell2*)&cells[0];
        dst[1] = *(const Cell2*)&cells[2];
    };

    auto compute_tile = [&](int t, int buf, float fdx, float fdy) {
        const int Yt = Y0 + t * TLH;
        const int y = Yt + ty;
        const int pos = y * W + x;

        const float xm = (float)x + fdx;
        const float ym = (float)y + fdy;
        const float x0f = floorf(xm);
        const float y0f = floorf(ym);
        const float tfx = xm - x0f;
        const float tfy = ym - y0f;

        float cx[4], cy[4];
        cubic_coeffs(tfx, cx);
        cubic_coeffs(tfy, cy);

        const int x0 = (int)x0f;
        const int y0 = (int)y0f;

        float a0, a1, a2;

        const unsigned ulx = (unsigned)(x0 - X + (RTX - 1));
        const unsigned uly = (unsigned)(y0 - Yt + (RTY - 1));

        if (ulx <= (unsigned)(CLS - 4) && uly <= (unsigned)(RWS - 4)) {
            const Cell* __restrict__ base = &lds[buf][uly * STR + ulx];
            __half2 cxh[4], cyh[4];
#pragma unroll
            for (int j = 0; j < 4; ++j) {
                cxh[j] = __float2half2_rn(cx[j]);
                cyh[j] = __float2half2_rn(cy[j]);
            }
            __half2 acc01 = __float2half2_rn(0.0f);
            __half2 acc2  = __float2half2_rn(0.0f);
#pragma unroll
            for (int i = 0; i < 4; ++i) {
                const Cell* __restrict__ row = base + i * STR;
                Cell t0 = row[0];
                Cell t1 = row[1];
                Cell t2 = row[2];
                Cell t3 = row[3];
                __half2 r01 = __hmul2(cxh[0], t0.a);
                r01 = __hfma2(cxh[1], t1.a, r01);
                r01 = __hfma2(cxh[2], t2.a, r01);
                r01 = __hfma2(cxh[3], t3.a, r01);
                __half2 r2 = __hmul2(cxh[0], t0.b);
                r2 = __hfma2(cxh[1], t1.b, r2);
                r2 = __hfma2(cxh[2], t2.b, r2);
                r2 = __hfma2(cxh[3], t3.b, r2);
                acc01 = __hfma2(cyh[i], r01, acc01);
                acc2  = __hfma2(cyh[i], r2, acc2);
            }
            a0 = __low2float(acc01);
            a1 = __high2float(acc01);
            a2 = __low2float(acc2);
        } else {
            // rare tail (|delta| >= ~6): direct clamped f32 global gathers
            a0 = a1 = a2 = 0.0f;
            int xs[4], rowoff[4];
#pragma unroll
            for (int o = 0; o < 4; ++o) {
                xs[o] = min(max(x0 - 1 + o, 0), W - 1);
                rowoff[o] = min(max(y0 - 1 + o, 0), H - 1) * W;
            }
#pragma unroll
            for (int i = 0; i < 4; ++i) {
                float w0 = cy[i] * cx[0], w1 = cy[i] * cx[1];
                float w2 = cy[i] * cx[2], w3 = cy[i] * cx[3];
                const float* r0 = ch0 + rowoff[i];
                const float* r1 = ch1 + rowoff[i];
                const float* r2 = ch2 + rowoff[i];
                a0 = fmaf(w0, r0[xs[0]], a0); a0 = fmaf(w1, r0[xs[1]], a0);
                a0 = fmaf(w2, r0[xs[2]], a0); a0 = fmaf(w3, r0[xs[3]], a0);
                a1 = fmaf(w0, r1[xs[0]], a1); a1 = fmaf(w1, r1[xs[1]], a1);
                a1 = fmaf(w2, r1[xs[2]], a1); a1 = fmaf(w3, r1[xs[3]], a1);
                a2 = fmaf(w0, r2[xs[0]], a2); a2 = fmaf(w1, r2[xs[1]], a2);
                a2 = fmaf(w2, r2[xs[2]], a2); a2 = fmaf(w3, r2[xs[3]], a2);
            }
        }

        out[(size_t)db * hw + pos] = a0;
        out[(size_t)(db + B) * hw + pos] = a1;
        out[(size_t)(db + 2 * B) * hw + pos] = a2;
    };

    // ---- prologue: stage tile 0 ----
    issue_delta(0);
    issue_stage(0);
    write_stage(0);
    __syncthreads();

    // ---- pipelined main loop ----
    for (int t = 0; t < TPB; ++t) {
        const float fdx = fdx_n;
        const float fdy = fdy_n;
        if (t + 1 < TPB) {
            issue_delta(t + 1);      // loads stay in flight during compute
            issue_stage(t + 1);
        }
        compute_tile(t, t & 1, fdx, fdy);
        if (t + 1 < TPB) {
            write_stage((t + 1) & 1);   // vmcnt wait happens here, post-compute
        }
        __syncthreads();
    }
}

extern "C" void kernel_launch(void* const* d_in, const int* in_sizes, int n_in,
                              void* d_out, int out_size, void* d_ws, size_t ws_size,
                              hipStream_t stream) {
    const float* img = (const float*)d_in[0];
    const float* dx  = (const float*)d_in[1];
    const float* dy  = (const float*)d_in[2];
    float* out = (float*)d_out;

    const int B = 8, C = 3, H = 1024, W = 1024;
    dim3 block(64, 16, 1);
    dim3 grid(W / 64, H / (TLH * TPB), B);
    warp_bicubic_kernel<<<grid, block, 0, stream>>>(img, dx, dy, out, B, C, H, W);
}